// Round 5
// baseline (3541.946 us; speedup 1.0000x reference)
//
#include <hip/hip_runtime.h>
#include <cstdint>
#include <cstddef>

// PlainRNN fused: h_{t+1} = tanh(h_t @ W_eff + b_eff), traj[t] = h_t @ W_h2o + b_h2o
// W_eff = W_h2h + W_h2o @ W_i2h  (recurrence composition removes x from the loop)
//
// Persistent kernel: 16 groups (16 batch rows each) x 16 blocks (72 of 1152 cols).
// Groups formed DYNAMICALLY per-XCD (HW_REG_XCC_ID + per-XCD slot counter).
//
// R10 = R7 skeleton (C=1, all 256 blocks) minus three serializers.
//   Ledger: R5 1600 (atomicAdd+serial poll) ; R6 3667 (poll flood, no backoff);
//   R7 1452 (store-flag + wave0 poll); R8 94ms (FALSIFIED: sc0 load cannot see
//   plain cross-CU stores — agent-scope path required); R9 2251 (FALSIFIED:
//   chain-multiplex = C x body serialization, no hiding possible).
//   R9's regression measured the split: body ~1.5us, sync ~1.3us per step.
//   At 1 wave/SIMD every latency is exposed, and 3 all-wave barriers/step
//   serialize the slowest wave's drains. R10 removes:
//   (1) release barrier: ALL waves poll the group's flags (self-release),
//       s_sleep(1) backoff retained (R6's melt was no-backoff, not pollers).
//   (2) drain barrier: per-(member,wave) flags. A wave's pass-1 cols are its
//       own (tile c owner = c&3); after ITS OWN s_waitcnt vmcnt(0) it flags.
//       64 flags/group (2 lines), consumers wait all 64.
//   (3) reduce barrier drains lgkmcnt ONLY (raw s_barrier) — skips the
//       compiler's vmcnt(0) store-ack drain at __syncthreads.
//   red race without release barrier -> parity double-buffer red[t&1].
//   h data unchanged: plain stores -> XCD L2; consumers plain-load + 4-slot
//   hbuf rotation (128KB/step streams the 32KB L1 -> always-fresh L2 hits).

#define BATCH  256
#define INPUT  128
#define HIDDEN 1024
#define OUTPUT 128
#define TSTEPS 512
#define NCAT   1152
#define NTILE  72
#define GROUPS 16
#define MEMB   16
#define NSLOT  4

// workspace layout (bytes)
#define WS_WFRAG 0u
#define WS_BEFF  2621440u
#define WS_HBUF  2629632u                 // 4 slots x 256x1024 f16 = 4x524288
#define WS_BAR   4726784u
// bar[] u32: [g*64 + mem*4 + wv] per-wave step flags (16 groups x 64, 2 lines each)
//            [1024 + xcc*32]     per-XCD slot counters (one-time)
#define BAR_U32S 1280

typedef _Float16 f16;
typedef _Float16 v8h __attribute__((ext_vector_type(8)));
typedef float    v4f __attribute__((ext_vector_type(4)));

__device__ __forceinline__ float fast_tanh(float x){
  float e = __expf(2.0f * x);
  return (e - 1.0f) / (e + 1.0f);
}

// ---- bias composition
__global__ void k_bias(const float* __restrict__ bi2h, const float* __restrict__ bh2h,
                       const float* __restrict__ bh2o, const float* __restrict__ Wi2h,
                       float* __restrict__ beff){
  int n = blockIdx.x*256 + threadIdx.x;
  if (n >= 1168) return;
  float v = 0.f;
  if (n < HIDDEN){
    v = bi2h[n] + bh2h[n];
    for (int j=0;j<INPUT;j++) v += bh2o[j]*Wi2h[j*HIDDEN + n];
  } else if (n < NCAT){
    v = bh2o[n - HIDDEN];
  }
  beff[n] = v;
}

// ---- h_1 = tanh(x0 @ W_i2h + b_i2h + b_h2h) -> slot 0
__global__ void k_h1(const float* __restrict__ x0, const float* __restrict__ Wi2h,
                     const float* __restrict__ bi2h, const float* __restrict__ bh2h,
                     f16* __restrict__ hbuf){
  int idx = blockIdx.x*256 + threadIdx.x;
  int m = idx >> 10, n = idx & 1023;
  float acc = bi2h[n] + bh2h[n];
  const float* xr = x0 + m*INPUT;
  for (int j=0;j<INPUT;j++) acc += xr[j]*Wi2h[j*HIDDEN + n];
  hbuf[idx] = (f16)fast_tanh(acc);
}

// ---- traj[0] = x_0
__global__ void k_copy0(const float* __restrict__ x0, float* __restrict__ out){
  int i = blockIdx.x*256 + threadIdx.x;
  out[i] = x0[i];
}

// ---- W fragment packing: [mem 16][wave 4][kk 8][c 5][lane 64][8 halves]
__global__ void k_wfrag(const float* __restrict__ Wh2h, const float* __restrict__ Wh2o,
                        const float* __restrict__ Wi2h, f16* __restrict__ Wfrag){
  int gid = blockIdx.x*256 + threadIdx.x;
  int lane = gid & 63;
  int fi = gid >> 6;
  int c = fi % 5, kk = (fi/5) & 7, wv = (fi/40) & 3, mem = fi/160;
  int k0 = wv*256 + kk*32 + (lane>>4)*8;
  int n  = mem*NTILE + c*16 + (lane & 15);
  f16 vals[8];
  if (n >= NCAT){
    #pragma unroll
    for (int j=0;j<8;j++) vals[j] = (f16)0.f;
  } else if (n >= HIDDEN){
    #pragma unroll
    for (int j=0;j<8;j++) vals[j] = (f16)Wh2o[(k0+j)*OUTPUT + (n-HIDDEN)];
  } else {
    float acc[8];
    #pragma unroll
    for (int j=0;j<8;j++) acc[j] = Wh2h[(k0+j)*HIDDEN + n];
    for (int q=0;q<INPUT;q++){
      float wi = Wi2h[q*HIDDEN + n];
      #pragma unroll
      for (int j=0;j<8;j++) acc[j] += Wh2o[(k0+j)*OUTPUT + q]*wi;
    }
    #pragma unroll
    for (int j=0;j<8;j++) vals[j] = (f16)acc[j];
  }
  v8h pack;
  #pragma unroll
  for (int j=0;j<8;j++) pack[j] = vals[j];
  *(v8h*)(Wfrag + (size_t)gid*8) = pack;
}

// ---- persistent recurrence kernel: 256 blocks x 256 threads, 1 block/CU (96KB dyn LDS)
__global__ void __launch_bounds__(256, 1)
k_rnn(const f16* __restrict__ Wfrag, const float* __restrict__ beff,
      f16* __restrict__ hbuf, unsigned int* __restrict__ bar,
      float* __restrict__ out){
  extern __shared__ char lds_raw[];
  // red parity double-buffer: +0 / +16384 (15360 B used each).
  // No release barrier anymore => step t's red reads can overlap step t+1's
  // writes from a faster wave; parity split makes that safe (intra-block skew
  // is bounded to <1 step by the reduce barrier).
  unsigned* s_slot = (unsigned*)(lds_raw + 32768);

  const int tid  = threadIdx.x;
  const int lane = tid & 63;
  const int wv   = tid >> 6;

  // Dynamic same-XCD group formation. 1 block/CU + grid==CU count => 32 blocks/XCD.
  // Group = xcc*2 + slot/16, member = slot%16: group shares one XCD L2 BY CONSTRUCTION.
  if (tid == 0){
    unsigned xcc;
    asm volatile("s_getreg_b32 %0, hwreg(HW_REG_XCC_ID)" : "=s"(xcc));
    xcc &= 7;
    unsigned slot = atomicAdd(&bar[1024 + xcc*32], 1u);  // one-time, device-scope
    *s_slot = xcc*32 + (slot & 31u);
  }
  __syncthreads();
  const unsigned sid = *s_slot;
  const int g   = sid >> 4;
  const int mem = sid & 15;
  if (g >= GROUPS) return;
  const int m0   = g * 16;
  const int n0   = mem * NTILE;
  const int quad = lane >> 4;
  const int l15  = lane & 15;

  // B fragments resident in registers for the whole 511-step loop
  v8h bw[8][5];
  {
    const f16* wp = Wfrag + ((size_t)((mem*4 + wv)*40)*64 + lane)*8;
    #pragma unroll
    for (int kk=0;kk<8;kk++)
      #pragma unroll
      for (int c=0;c<5;c++)
        bw[kk][c] = *(const v8h*)(wp + (size_t)((kk*5+c)*64)*8);
  }

  // Bias hoisted to registers (beff load always missed L1 — A-stream evicts it).
  float bown[2] = {0.f, 0.f};
  #pragma unroll
  for (int c=0;c<5;c++){
    if ((c & 3) == wv){
      int colT = c*16 + l15;
      int col  = n0 + colT;
      if (colT < NTILE && col < NCAT) bown[c>>2] = beff[col];
    }
  }

  const int kbase = wv*256;
  unsigned int* flg    = bar + g*64;        // 64 per-wave flags, 2 lines
  const int     myflag = mem*4 + wv;

  for (int t=1; t<TSTEPS; ++t){
    // ---- self-release poll: EVERY wave polls all 64 group flags (one coalesced
    // 256B load per round), agent-relaxed, s_sleep(1) backoff (R6's melt was
    // no-backoff, not poller count). No release barrier: a wave starts its
    // A-loads the moment it sees all flags >= t-1.
    // Bounded: if broken, visible absmax failure, never a hang.
    {
      const unsigned target = (unsigned)(t-1);
      unsigned tries = 0;
      for (;;){
        unsigned f = __hip_atomic_load(flg + lane, __ATOMIC_RELAXED,
                                       __HIP_MEMORY_SCOPE_AGENT);
        if (__all((int)(f >= target))) break;
        if (++tries > 2048u) break;
        __builtin_amdgcn_s_sleep(1);
      }
    }

    const f16* hin  = hbuf + (size_t)((t-1)&(NSLOT-1))*(BATCH*HIDDEN);
    f16*       hout = hbuf + (size_t)(t&(NSLOT-1))*(BATCH*HIDDEN);
    float*     red  = (float*)(lds_raw + (size_t)(t & 1)*16384);

    // A fragments: plain vector loads. 4-slot rotation guarantees L1 eviction
    // (128KB/step streamed) => miss L1, hit the shared XCD L2 (always fresh).
    // lane holds A[m=lane&15][k=quad*8+j]; waves read disjoint K slices.
    v8h af[8];
    {
      const v8h* abase = (const v8h*)(hin + (size_t)(m0 + l15)*HIDDEN + kbase + quad*8);
      #pragma unroll
      for (int kk=0;kk<8;kk++)
        af[kk] = abase[kk*4];            // stride 32 halves = 4 v8h
    }

    v4f acc[5];
    #pragma unroll
    for (int c=0;c<5;c++){ v4f z = {0.f,0.f,0.f,0.f}; acc[c] = z; }

    #pragma unroll
    for (int kk=0;kk<8;kk++){
      #pragma unroll
      for (int c=0;c<5;c++)
        acc[c] = __builtin_amdgcn_mfma_f32_16x16x32_f16(af[kk], bw[kk][c], acc[c], 0,0,0);
    }

    // cross-wave K reduction via LDS (parity buffer). tile c owner = c&3.
    #pragma unroll
    for (int c=0;c<5;c++){
      int owner = c & 3;
      if (wv != owner){
        int rank = (wv > owner) ? wv-1 : wv;
        *(v4f*)(red + ((size_t)(c*3 + rank)*64 + lane)*4) = acc[c];
      }
    }
    // reduce barrier: LDS visibility needs lgkmcnt(0) ONLY — raw s_barrier
    // skips __syncthreads' vmcnt(0) store-ack drain (stores from the previous
    // phases are drained per-wave before the flag instead).
    __builtin_amdgcn_sched_barrier(0);
    asm volatile("s_waitcnt lgkmcnt(0)" ::: "memory");
    __builtin_amdgcn_s_barrier();
    __builtin_amdgcn_sched_barrier(0);

    // pass 1: hidden columns (consumed by the group next step) -> plain stores
    // into the XCD L2. This wave's cols only (owner = c&3 == wv).
    #pragma unroll
    for (int c=0;c<5;c++){
      if ((c & 3) == wv){
        int colT = c*16 + l15;
        int col  = n0 + colT;
        if (col < HIDDEN && colT < NTILE){
          v4f s = acc[c];
          #pragma unroll
          for (int r=0;r<3;r++) s += *(const v4f*)(red + ((size_t)(c*3 + r)*64 + lane)*4);
          float b = bown[c>>2];
          #pragma unroll
          for (int r=0;r<4;r++){
            float v = fast_tanh(s[r] + b);
            hout[(size_t)(m0 + quad*4 + r)*HIDDEN + col] = (f16)v;  // C/D: col=lane&15,row=quad*4+r
          }
        }
      }
    }

    // per-wave drain + per-wave flag: this wave's h stores are the only ones
    // consumers need from THIS flag (wave owns its cols). No all-wave barrier.
    asm volatile("s_waitcnt vmcnt(0)" ::: "memory");
    if (lane == 0)
      __hip_atomic_store(flg + myflag, (unsigned)t, __ATOMIC_RELAXED,
                         __HIP_MEMORY_SCOPE_AGENT);

    // pass 2: y columns (consumed by nobody) — after the flag, off the
    // critical path; red[t&1] stable until t+2 (parity).
    #pragma unroll
    for (int c=0;c<5;c++){
      if ((c & 3) == wv){
        int colT = c*16 + l15;
        int col  = n0 + colT;
        if (col >= HIDDEN && colT < NTILE){
          v4f s = acc[c];
          #pragma unroll
          for (int r=0;r<3;r++) s += *(const v4f*)(red + ((size_t)(c*3 + r)*64 + lane)*4);
          float b = bown[c>>2];
          float* op = out + (size_t)t*(BATCH*OUTPUT) + (col - HIDDEN);
          #pragma unroll
          for (int r=0;r<4;r++)
            op[(size_t)(m0 + quad*4 + r)*OUTPUT] = s[r] + b;
        }
      }
    }
  }
}

extern "C" void kernel_launch(void* const* d_in, const int* in_sizes, int n_in,
                              void* d_out, int out_size, void* d_ws, size_t ws_size,
                              hipStream_t stream){
  const float* x0   = (const float*)d_in[0];
  const float* Wi2h = (const float*)d_in[1];
  const float* bi2h = (const float*)d_in[2];
  const float* Wh2h = (const float*)d_in[3];
  const float* bh2h = (const float*)d_in[4];
  const float* Wh2o = (const float*)d_in[5];
  const float* bh2o = (const float*)d_in[6];
  float* out = (float*)d_out;
  char* ws = (char*)d_ws;

  f16*          Wfrag = (f16*)(ws + WS_WFRAG);
  float*        beff  = (float*)(ws + WS_BEFF);
  f16*          hbuf  = (f16*)(ws + WS_HBUF);
  unsigned int* bar   = (unsigned int*)(ws + WS_BAR);

  hipMemsetAsync(bar, 0, BAR_U32S*sizeof(unsigned int), stream);
  k_bias <<<5,    256, 0, stream>>>(bi2h, bh2h, bh2o, Wi2h, beff);
  k_h1   <<<1024, 256, 0, stream>>>(x0, Wi2h, bi2h, bh2h, hbuf);
  k_copy0<<<128,  256, 0, stream>>>(x0, out);
  k_wfrag<<<640,  256, 0, stream>>>(Wh2h, Wh2o, Wi2h, Wfrag);

  // 96KB dynamic LDS forces 1 block/CU -> all 256 blocks co-resident, 32 per XCD,
  // 1 wave/SIMD -> full VGPR budget for register-resident W fragments.
  hipFuncSetAttribute((const void*)k_rnn, hipFuncAttributeMaxDynamicSharedMemorySize, 98304);
  k_rnn<<<256, 256, 98304, stream>>>(Wfrag, beff, hbuf, bar, out);
}